// Round 11
// baseline (351.059 us; speedup 1.0000x reference)
//
#include <hip/hip_runtime.h>
#include <math.h>

#define WG 256
#define NB 256             // radix buckets (node-range 512 each -> N <= 131072)
#define BSHIFT 9
#define NBLK 256           // partition blocks

typedef float vf2 __attribute__((ext_vector_type(2)));
typedef short bf16x8 __attribute__((ext_vector_type(8)));
typedef float f32x4 __attribute__((ext_vector_type(4)));

#define XS_STRIDE 136      // ushort stride, 16B-aligned rows + conflict pad
#define WT_STRIDE 136
#define C_STRIDE 132       // float stride, 16B-aligned

__device__ __forceinline__ int lower_bound_i(const int* __restrict__ a, int n, int key) {
    int lo = 0, hi = n;
    while (lo < hi) { int mid = (lo + hi) >> 1; if (a[mid] < key) lo = mid + 1; else hi = mid; }
    return lo;
}

// ---- fp8 (OCP e4m3) helpers ------------------------------------------------
__device__ __forceinline__ void fp8x8_to_f8(uint2 raw, float* f) {
    vf2 a = __builtin_amdgcn_cvt_pk_f32_fp8((int)raw.x, false);
    vf2 b = __builtin_amdgcn_cvt_pk_f32_fp8((int)raw.x, true);
    vf2 c = __builtin_amdgcn_cvt_pk_f32_fp8((int)raw.y, false);
    vf2 d = __builtin_amdgcn_cvt_pk_f32_fp8((int)raw.y, true);
    f[0]=a.x; f[1]=a.y; f[2]=b.x; f[3]=b.y; f[4]=c.x; f[5]=c.y; f[6]=d.x; f[7]=d.y;
}
__device__ __forceinline__ void fp8x16_to_f(uint4 raw, float* f) {
    uint2 lo, hi;
    lo.x = raw.x; lo.y = raw.y; hi.x = raw.z; hi.y = raw.w;
    fp8x8_to_f8(lo, f);
    fp8x8_to_f8(hi, f + 8);
}
__device__ __forceinline__ unsigned int f4_to_fp8x4(float x, float y, float z, float w) {
    int v = __builtin_amdgcn_cvt_pk_fp8_f32(x, y, 0, false);
    v = __builtin_amdgcn_cvt_pk_fp8_f32(z, w, v, true);
    return (unsigned int)v;
}
__device__ __forceinline__ unsigned short f_to_bf_trunc(float f) {
    return (unsigned short)(__float_as_uint(f) >> 16);
}
__device__ __forceinline__ unsigned short f_to_bf_rne(float f) {
    unsigned int u = __float_as_uint(f);
    u += 0x7FFFu + ((u >> 16) & 1u);
    return (unsigned short)(u >> 16);
}

// ---- CSR build: deterministic radix partition (no global atomics) ----------

__global__ __launch_bounds__(256) void k_cnt(const int* __restrict__ edst, int E,
                                             int* __restrict__ gcounts) {
    __shared__ int hist[NB];
    int t = threadIdx.x, blk = blockIdx.x;
    if (t < NB) hist[t] = 0;
    __syncthreads();
    int chunk = (E + NBLK - 1) / NBLK;
    int e0 = blk * chunk, e1 = min(E, e0 + chunk);
    for (int e = e0 + t; e < e1; e += 256) atomicAdd(&hist[edst[e] >> BSHIFT], 1);
    __syncthreads();
    if (t < NB) gcounts[t * NBLK + blk] = hist[t];
}

__global__ __launch_bounds__(256) void k_scanA(int* __restrict__ gcounts,
                                               int* __restrict__ bsum) {
    __shared__ int wtot[4];
    int t = threadIdx.x;
    int base = blockIdx.x * 1024 + t * 4;
    int4 v = *(const int4*)&gcounts[base];
    int s = v.x + v.y + v.z + v.w;
    int lane = t & 63, wid = t >> 6;
    int x = s;
#pragma unroll
    for (int d = 1; d < 64; d <<= 1) { int y = __shfl_up(x, d); if (lane >= d) x += y; }
    if (lane == 63) wtot[wid] = x;
    __syncthreads();
    int woff = 0;
    for (int w = 0; w < wid; w++) woff += wtot[w];
    int excl = woff + x - s;
    int4 o;
    o.x = excl; o.y = excl + v.x; o.z = o.y + v.y; o.w = o.z + v.z;
    *(int4*)&gcounts[base] = o;
    if (t == 255) bsum[blockIdx.x] = woff + x;
}

__global__ void k_scanB(int* __restrict__ bsum) {
    int t = threadIdx.x;   // 64 threads
    int v = bsum[t];
    int x = v;
#pragma unroll
    for (int d = 1; d < 64; d <<= 1) { int y = __shfl_up(x, d); if (t >= d) x += y; }
    bsum[t] = x - v;
}

// scatter edges packed as (src << 9) | (dst & 511)
__global__ __launch_bounds__(256) void k_scat(const int* __restrict__ esrc,
        const int* __restrict__ edst, int E,
        const int* __restrict__ gcounts, const int* __restrict__ bsum,
        int* __restrict__ pairs) {
    __shared__ int cur[NB];
    int t = threadIdx.x, blk = blockIdx.x;
    if (t < NB) {
        int idx = t * NBLK + blk;
        cur[t] = gcounts[idx] + bsum[idx >> 10];
    }
    __syncthreads();
    int chunk = (E + NBLK - 1) / NBLK;
    int e0 = blk * chunk, e1 = min(E, e0 + chunk);
    for (int e = e0 + t; e < e1; e += 256) {
        int d = edst[e], s = esrc[e];
        int pos = atomicAdd(&cur[d >> BSHIFT], 1);
        pairs[pos] = (s << BSHIFT) | (d & ((1 << BSHIFT) - 1));
    }
}

__global__ __launch_bounds__(256) void k_build(const int* __restrict__ pairs,
        const int* __restrict__ gcounts, const int* __restrict__ bsum, int N, int E,
        int* __restrict__ offs, int* __restrict__ srcs, float* __restrict__ dis) {
    __shared__ int cnt[512];
    __shared__ int wtot[4];
    int b = blockIdx.x, t = threadIdx.x;
    int n0 = b << BSHIFT;
    cnt[2 * t] = 0; cnt[2 * t + 1] = 0;
    __syncthreads();
    int i0 = b * NBLK, i1 = (b + 1) * NBLK;
    int bs = gcounts[i0] + bsum[i0 >> 10];
    int be = gcounts[i1] + bsum[i1 >> 10];
    int m = be - bs;
    const int* pb = &pairs[bs];
    for (int i = t; i < m; i += 256) {
        int p = pb[i];
        atomicAdd(&cnt[p & 511], 1);
    }
    __syncthreads();
    int v0 = cnt[2 * t], v1 = cnt[2 * t + 1];
    int ts = v0 + v1;
    int lane = t & 63, wid = t >> 6;
    int x = ts;
    #pragma unroll
    for (int d = 1; d < 64; d <<= 1) { int y = __shfl_up(x, d); if (lane >= d) x += y; }
    if (lane == 63) wtot[wid] = x;
    __syncthreads();
    int woff = 0;
    for (int w = 0; w < wid; w++) woff += wtot[w];
    int excl = woff + x - ts;
    int o0 = excl, o1 = excl + v0;
    cnt[2 * t] = o0; cnt[2 * t + 1] = o1;
    int n = n0 + 2 * t;
    if (n + 0 < N) { offs[n + 0] = bs + o0; dis[n + 0] = rsqrtf((float)(v0 + 1)); }
    if (n + 1 < N) { offs[n + 1] = bs + o1; dis[n + 1] = rsqrtf((float)(v1 + 1)); }
    if (b == gridDim.x - 1 && t == 255) offs[N] = E;
    __syncthreads();
    for (int i = t; i < m; i += 256) {
        int p = pb[i];
        int pos = atomicAdd(&cnt[p & 511], 1);
        srcs[bs + pos] = p >> BSHIFT;
    }
}

// ---- W transpose to bf16: WT[j][k] = bf16(W[k][j]) -------------------------
__global__ __launch_bounds__(256) void k_wt(const float* __restrict__ W,
                                            unsigned short* __restrict__ wt) {
    int idx = blockIdx.x * 256 + threadIdx.x;
    int k = idx >> 7, j = idx & 127;
    float v = W[k * 128 + j];
    wt[j * 128 + k] = f_to_bf_rne(v);
}

// ---- Layer kernels --------------------------------------------------------

// y[n] = dis[n] * (an, px, py, pz)   — 16B fp32 rows for the 4-dim gather
__global__ void k_y(const float* __restrict__ an, const float* __restrict__ pos,
                    const float* __restrict__ dis, float4* __restrict__ y, int N) {
    int n = blockIdx.x * blockDim.x + threadIdx.x;
    if (n >= N) return;
    float dn = dis[n];
    float4 v;
    v.x = dn * an[n];
    v.y = dn * pos[n * 3 + 0];
    v.z = dn * pos[n * 3 + 1];
    v.w = dn * pos[n * 3 + 2];
    y[n] = v;
}

// Layer0 (algebraic fold): x1[n] = relu(b0 + dis[n]*(y[n]+Σ y[src]) @ W0), fp8.
// 1 thread per node; 4-dim gather (16B rows, L2-resident 1.6MB buffer).
__global__ __launch_bounds__(256) void k_agg0t(const float4* __restrict__ y,
        const float* __restrict__ W0, const float* __restrict__ b0,
        const float* __restrict__ dis, const int* __restrict__ offs,
        const int* __restrict__ srcs, unsigned int* __restrict__ h, int N) {
    int n = blockIdx.x * blockDim.x + threadIdx.x;
    if (n >= N) return;
    float4 acc = y[n];   // self-loop
    int e0 = offs[n], e1 = offs[n + 1];
    int e = e0;
    for (; e + 4 <= e1; e += 4) {
        float4 r0 = y[srcs[e + 0]];
        float4 r1 = y[srcs[e + 1]];
        float4 r2 = y[srcs[e + 2]];
        float4 r3 = y[srcs[e + 3]];
        acc.x += (r0.x + r1.x) + (r2.x + r3.x);
        acc.y += (r0.y + r1.y) + (r2.y + r3.y);
        acc.z += (r0.z + r1.z) + (r2.z + r3.z);
        acc.w += (r0.w + r1.w) + (r2.w + r3.w);
    }
    for (; e < e1; ++e) {
        float4 r = y[srcs[e]];
        acc.x += r.x; acc.y += r.y; acc.z += r.z; acc.w += r.w;
    }
    float dn = dis[n];
    acc.x *= dn; acc.y *= dn; acc.z *= dn; acc.w *= dn;
    // matvec: out[j] = relu(b0[j] + acc · W0[:,j]); W0 loads are wave-uniform
#pragma unroll
    for (int c = 0; c < 8; c++) {
        float o[16];
#pragma unroll
        for (int q = 0; q < 4; q++) {
            const float4 bq = *(const float4*)&b0[c * 16 + q * 4];
            const float4 w0q = *(const float4*)&W0[0 * 128 + c * 16 + q * 4];
            const float4 w1q = *(const float4*)&W0[1 * 128 + c * 16 + q * 4];
            const float4 w2q = *(const float4*)&W0[2 * 128 + c * 16 + q * 4];
            const float4 w3q = *(const float4*)&W0[3 * 128 + c * 16 + q * 4];
            o[q*4+0] = fmaxf(bq.x + acc.x*w0q.x + acc.y*w1q.x + acc.z*w2q.x + acc.w*w3q.x, 0.f);
            o[q*4+1] = fmaxf(bq.y + acc.x*w0q.y + acc.y*w1q.y + acc.z*w2q.y + acc.w*w3q.y, 0.f);
            o[q*4+2] = fmaxf(bq.z + acc.x*w0q.z + acc.y*w1q.z + acc.z*w2q.z + acc.w*w3q.z, 0.f);
            o[q*4+3] = fmaxf(bq.w + acc.x*w0q.w + acc.y*w1q.w + acc.z*w2q.w + acc.w*w3q.w, 0.f);
        }
        uint4 outv;
        outv.x = f4_to_fp8x4(o[0], o[1], o[2], o[3]);
        outv.y = f4_to_fp8x4(o[4], o[5], o[6], o[7]);
        outv.z = f4_to_fp8x4(o[8], o[9], o[10], o[11]);
        outv.w = f4_to_fp8x4(o[12], o[13], o[14], o[15]);
        *(uint4*)&h[(size_t)n * 32 + c * 4] = outv;
    }
}

// MFMA GEMM: h'[n][f] = (relu(x[n]) @ W)[f] * dis[n]
__global__ __launch_bounds__(256) void k_gemm(const unsigned int* __restrict__ x,
                                              const unsigned short* __restrict__ wt,
                                              const float* __restrict__ dis,
                                              unsigned int* __restrict__ h, int N) {
    __shared__ __align__(16) char ldsb[(64 * XS_STRIDE + 128 * WT_STRIDE) * 2];
    unsigned short* xs  = (unsigned short*)ldsb;
    unsigned short* wtl = xs + 64 * XS_STRIDE;
    float* Cs = (float*)ldsb;

    int t = threadIdx.x;
    int n0 = blockIdx.x * 64;

    {
        const uint2* xg = (const uint2*)(x + (size_t)n0 * 32);
        int validq = min(64, N - n0) * 16;
#pragma unroll
        for (int i = 0; i < 4; i++) {
            int idx = t + i * 256;
            int row = idx >> 4, part = idx & 15;
            float f[8];
            if (idx < validq) {
                fp8x8_to_f8(xg[idx], f);
#pragma unroll
                for (int k = 0; k < 8; k++) f[k] = fmaxf(f[k], 0.f);
            } else {
#pragma unroll
                for (int k = 0; k < 8; k++) f[k] = 0.f;
            }
            bf16x8 v;
#pragma unroll
            for (int k = 0; k < 8; k++) v[k] = (short)f_to_bf_trunc(f[k]);
            *(bf16x8*)&xs[row * XS_STRIDE + part * 8] = v;
        }
    }
    {
        const uint4* wg = (const uint4*)wt;
#pragma unroll
        for (int i = 0; i < 8; i++) {
            int idx = t + i * 256;
            int j = idx >> 4, part = idx & 15;
            uint4 v = wg[idx];
            *(uint4*)&wtl[j * WT_STRIDE + part * 8] = v;
        }
    }
    __syncthreads();

    int lane = t & 63, wv = t >> 6;
    int m = lane & 15, quad = lane >> 4;
    int rowbase = wv * 16;

    f32x4 acc[8];
#pragma unroll
    for (int c = 0; c < 8; c++) acc[c] = (f32x4){0.f, 0.f, 0.f, 0.f};

#pragma unroll
    for (int kt = 0; kt < 4; kt++) {
        bf16x8 a = *(bf16x8*)&xs[(rowbase + m) * XS_STRIDE + kt * 32 + quad * 8];
#pragma unroll
        for (int c = 0; c < 8; c++) {
            bf16x8 b = *(bf16x8*)&wtl[(c * 16 + m) * WT_STRIDE + kt * 32 + quad * 8];
            acc[c] = __builtin_amdgcn_mfma_f32_16x16x32_bf16(a, b, acc[c], 0, 0, 0);
        }
    }
    __syncthreads();

#pragma unroll
    for (int c = 0; c < 8; c++) {
#pragma unroll
        for (int r = 0; r < 4; r++) {
            Cs[(rowbase + quad * 4 + r) * C_STRIDE + c * 16 + m] = acc[c][r];
        }
    }
    __syncthreads();

    int fq = t & 31, ng = t >> 5;
#pragma unroll
    for (int i = 0; i < 8; i++) {
        int lrow = ng * 8 + i;
        int n = n0 + lrow;
        if (n < N) {
            float4 v = *(const float4*)&Cs[lrow * C_STRIDE + 4 * fq];
            float dn = dis[n];
            h[(size_t)n * 32 + fq] = f4_to_fp8x4(v.x * dn, v.y * dn, v.z * dn, v.w * dn);
        }
    }
}

// mid-layer agg: agg[n] = b + dis[n]*(h'[n] + sum_src h'[src]); fp8 (pre-relu).
// block = 256 = 32 nodes x 8 lanes; uint4 loads; unroll x8
__global__ __launch_bounds__(256) void k_agg(const unsigned int* __restrict__ h,
                      const float* __restrict__ bias,
                      const float* __restrict__ dis, const int* __restrict__ offs,
                      const int* __restrict__ srcs, unsigned int* __restrict__ agg, int N) {
    int fq = threadIdx.x & 7, ng = threadIdx.x >> 3;
    int n = blockIdx.x * 32 + ng;
    if (n >= N) return;
    const uint4* hp4 = (const uint4*)h;
    float acc[16], tmp[16];
    fp8x16_to_f(hp4[(size_t)n * 8 + fq], acc);
    int e0 = offs[n], e1 = offs[n + 1];
    int e = e0;
    for (; e + 8 <= e1; e += 8) {
        uint4 r0 = hp4[(size_t)srcs[e + 0] * 8 + fq];
        uint4 r1 = hp4[(size_t)srcs[e + 1] * 8 + fq];
        uint4 r2 = hp4[(size_t)srcs[e + 2] * 8 + fq];
        uint4 r3 = hp4[(size_t)srcs[e + 3] * 8 + fq];
        uint4 r4 = hp4[(size_t)srcs[e + 4] * 8 + fq];
        uint4 r5 = hp4[(size_t)srcs[e + 5] * 8 + fq];
        uint4 r6 = hp4[(size_t)srcs[e + 6] * 8 + fq];
        uint4 r7 = hp4[(size_t)srcs[e + 7] * 8 + fq];
        fp8x16_to_f(r0, tmp);
#pragma unroll
        for (int k = 0; k < 16; k++) acc[k] += tmp[k];
        fp8x16_to_f(r1, tmp);
#pragma unroll
        for (int k = 0; k < 16; k++) acc[k] += tmp[k];
        fp8x16_to_f(r2, tmp);
#pragma unroll
        for (int k = 0; k < 16; k++) acc[k] += tmp[k];
        fp8x16_to_f(r3, tmp);
#pragma unroll
        for (int k = 0; k < 16; k++) acc[k] += tmp[k];
        fp8x16_to_f(r4, tmp);
#pragma unroll
        for (int k = 0; k < 16; k++) acc[k] += tmp[k];
        fp8x16_to_f(r5, tmp);
#pragma unroll
        for (int k = 0; k < 16; k++) acc[k] += tmp[k];
        fp8x16_to_f(r6, tmp);
#pragma unroll
        for (int k = 0; k < 16; k++) acc[k] += tmp[k];
        fp8x16_to_f(r7, tmp);
#pragma unroll
        for (int k = 0; k < 16; k++) acc[k] += tmp[k];
    }
    for (; e + 4 <= e1; e += 4) {
        uint4 r0 = hp4[(size_t)srcs[e + 0] * 8 + fq];
        uint4 r1 = hp4[(size_t)srcs[e + 1] * 8 + fq];
        uint4 r2 = hp4[(size_t)srcs[e + 2] * 8 + fq];
        uint4 r3 = hp4[(size_t)srcs[e + 3] * 8 + fq];
        fp8x16_to_f(r0, tmp);
#pragma unroll
        for (int k = 0; k < 16; k++) acc[k] += tmp[k];
        fp8x16_to_f(r1, tmp);
#pragma unroll
        for (int k = 0; k < 16; k++) acc[k] += tmp[k];
        fp8x16_to_f(r2, tmp);
#pragma unroll
        for (int k = 0; k < 16; k++) acc[k] += tmp[k];
        fp8x16_to_f(r3, tmp);
#pragma unroll
        for (int k = 0; k < 16; k++) acc[k] += tmp[k];
    }
    for (; e < e1; ++e) {
        fp8x16_to_f(hp4[(size_t)srcs[e] * 8 + fq], tmp);
#pragma unroll
        for (int k = 0; k < 16; k++) acc[k] += tmp[k];
    }
    float dn = dis[n];
    float bv[16];
    *(float4*)&bv[0]  = *(const float4*)&bias[fq * 16 + 0];
    *(float4*)&bv[4]  = *(const float4*)&bias[fq * 16 + 4];
    *(float4*)&bv[8]  = *(const float4*)&bias[fq * 16 + 8];
    *(float4*)&bv[12] = *(const float4*)&bias[fq * 16 + 12];
    float o[16];
#pragma unroll
    for (int k = 0; k < 16; k++) o[k] = bv[k] + dn * acc[k];
    uint4 outv;
    outv.x = f4_to_fp8x4(o[0], o[1], o[2], o[3]);
    outv.y = f4_to_fp8x4(o[4], o[5], o[6], o[7]);
    outv.z = f4_to_fp8x4(o[8], o[9], o[10], o[11]);
    outv.w = f4_to_fp8x4(o[12], o[13], o[14], o[15]);
    *(uint4*)&agg[(size_t)n * 32 + fq * 4] = outv;
}

// Final agg + pool fused: pooled[g] += relu(b + dis[n]*(h'[n]+Σ h'[src])).
// Same gather shape as k_agg; per-block LDS accumulation over up to 4 graphs
// (batch sorted; fallback to global atomics beyond).
__global__ __launch_bounds__(256) void k_aggp(const unsigned int* __restrict__ h,
                      const float* __restrict__ bias,
                      const float* __restrict__ dis, const int* __restrict__ offs,
                      const int* __restrict__ srcs, const int* __restrict__ batch,
                      float* __restrict__ pooled, int N) {
    __shared__ float pg[4 * 128];
    int t = threadIdx.x;
    pg[t] = 0.f; pg[t + 256] = 0.f;
    __syncthreads();
    int fq = t & 7, ng = t >> 3;
    int nblk0 = blockIdx.x * 32;
    int gbase = batch[min(nblk0, N - 1)];
    int n = nblk0 + ng;
    if (n < N) {
        const uint4* hp4 = (const uint4*)h;
        float acc[16], tmp[16];
        fp8x16_to_f(hp4[(size_t)n * 8 + fq], acc);
        int e0 = offs[n], e1 = offs[n + 1];
        int e = e0;
        for (; e + 8 <= e1; e += 8) {
            uint4 r0 = hp4[(size_t)srcs[e + 0] * 8 + fq];
            uint4 r1 = hp4[(size_t)srcs[e + 1] * 8 + fq];
            uint4 r2 = hp4[(size_t)srcs[e + 2] * 8 + fq];
            uint4 r3 = hp4[(size_t)srcs[e + 3] * 8 + fq];
            uint4 r4 = hp4[(size_t)srcs[e + 4] * 8 + fq];
            uint4 r5 = hp4[(size_t)srcs[e + 5] * 8 + fq];
            uint4 r6 = hp4[(size_t)srcs[e + 6] * 8 + fq];
            uint4 r7 = hp4[(size_t)srcs[e + 7] * 8 + fq];
            fp8x16_to_f(r0, tmp);
#pragma unroll
            for (int k = 0; k < 16; k++) acc[k] += tmp[k];
            fp8x16_to_f(r1, tmp);
#pragma unroll
            for (int k = 0; k < 16; k++) acc[k] += tmp[k];
            fp8x16_to_f(r2, tmp);
#pragma unroll
            for (int k = 0; k < 16; k++) acc[k] += tmp[k];
            fp8x16_to_f(r3, tmp);
#pragma unroll
            for (int k = 0; k < 16; k++) acc[k] += tmp[k];
            fp8x16_to_f(r4, tmp);
#pragma unroll
            for (int k = 0; k < 16; k++) acc[k] += tmp[k];
            fp8x16_to_f(r5, tmp);
#pragma unroll
            for (int k = 0; k < 16; k++) acc[k] += tmp[k];
            fp8x16_to_f(r6, tmp);
#pragma unroll
            for (int k = 0; k < 16; k++) acc[k] += tmp[k];
            fp8x16_to_f(r7, tmp);
#pragma unroll
            for (int k = 0; k < 16; k++) acc[k] += tmp[k];
        }
        for (; e < e1; ++e) {
            fp8x16_to_f(hp4[(size_t)srcs[e] * 8 + fq], tmp);
#pragma unroll
            for (int k = 0; k < 16; k++) acc[k] += tmp[k];
        }
        float dn = dis[n];
        float bv[16];
        *(float4*)&bv[0]  = *(const float4*)&bias[fq * 16 + 0];
        *(float4*)&bv[4]  = *(const float4*)&bias[fq * 16 + 4];
        *(float4*)&bv[8]  = *(const float4*)&bias[fq * 16 + 8];
        *(float4*)&bv[12] = *(const float4*)&bias[fq * 16 + 12];
        int g = batch[n];
        int idx = g - gbase;
        if (idx < 4) {
            float* dst = &pg[idx * 128 + fq * 16];
#pragma unroll
            for (int k = 0; k < 16; k++)
                atomicAdd(&dst[k], fmaxf(bv[k] + dn * acc[k], 0.f));
        } else {
            float* dst = &pooled[g * 128 + fq * 16];
#pragma unroll
            for (int k = 0; k < 16; k++)
                atomicAdd(&dst[k], fmaxf(bv[k] + dn * acc[k], 0.f));
        }
    }
    __syncthreads();
    // flush LDS slices (each thread 2 entries)
#pragma unroll
    for (int i = 0; i < 2; i++) {
        int e2 = t + i * 256;
        int gi = gbase + (e2 >> 7);
        float v = pg[e2];
        if (gi < 64 && v != 0.f) atomicAdd(&pooled[gi * 128 + (e2 & 127)], v);
    }
}

// ---- Head ------------------------------------------------------------------

__global__ void k_head(const float* __restrict__ pooled, const int* __restrict__ batch,
                       const float* __restrict__ linW, const float* __restrict__ linb,
                       float* __restrict__ out, int N) {
    int g = threadIdx.x;
    if (g >= 64) return;
    int start = lower_bound_i(batch, N, g);
    int end   = lower_bound_i(batch, N, g + 1);
    float cnt = fmaxf((float)(end - start), 1.0f);
    float logits[8];
#pragma unroll
    for (int j = 0; j < 8; j++) logits[j] = linb[j];
    for (int f = 0; f < 128; f++) {
        float p = pooled[g * 128 + f] / cnt;
#pragma unroll
        for (int j = 0; j < 8; j++) logits[j] += p * linW[f * 8 + j];
    }
    float m = logits[0];
#pragma unroll
    for (int j = 1; j < 8; j++) m = fmaxf(m, logits[j]);
    float s = 0.f;
    float e[8];
#pragma unroll
    for (int j = 0; j < 8; j++) { e[j] = expf(logits[j] - m); s += e[j]; }
#pragma unroll
    for (int j = 0; j < 8; j++) out[g * 8 + j] = e[j] / s;
}

// ---- Launch ---------------------------------------------------------------

extern "C" void kernel_launch(void* const* d_in, const int* in_sizes, int n_in,
                              void* d_out, int out_size, void* d_ws, size_t ws_size,
                              hipStream_t stream) {
    const float* an   = (const float*)d_in[0];
    const float* pos  = (const float*)d_in[1];
    const float* W0   = (const float*)d_in[2];
    const float* b0   = (const float*)d_in[3];
    const float* W1   = (const float*)d_in[4];
    const float* b1   = (const float*)d_in[5];
    const float* W2   = (const float*)d_in[6];
    const float* b2   = (const float*)d_in[7];
    const float* linW = (const float*)d_in[8];
    const float* linb = (const float*)d_in[9];
    const int*   ei   = (const int*)d_in[10];
    const int*   batch= (const int*)d_in[11];

    int N = in_sizes[0];
    int E = in_sizes[10] / 2;
    const int* esrc = ei;
    const int* edst = ei + E;
    int nb = (N + (1 << BSHIFT) - 1) >> BSHIFT;   // 196 for N=100000

    char* p = (char*)d_ws;
    auto carve = [&](size_t bytes) -> void* {
        void* r = (void*)p;
        p += (bytes + 255) & ~(size_t)255;
        return r;
    };
    unsigned int* bufA = (unsigned int*)carve((size_t)N * 128);   // fp8 rows
    unsigned int* bufB = (unsigned int*)carve((size_t)N * 128);
    float* dis    = (float*)carve((size_t)N * 4);
    float4* ybuf  = (float4*)carve((size_t)N * 16);
    int*   offs   = (int*)  carve((size_t)(N + 1) * 4);
    int*   srcs   = (int*)  carve((size_t)E * 4);
    int*   pairs  = (int*)  carve((size_t)E * 4);
    int*   gcounts= (int*)  carve((size_t)NB * NBLK * 4);
    int*   bsum   = (int*)  carve(64 * 4);
    unsigned short* wt1 = (unsigned short*)carve(128 * 128 * 2);
    unsigned short* wt2 = (unsigned short*)carve(128 * 128 * 2);
    float* pooled = (float*)carve(64 * 128 * 4);

    hipMemsetAsync(pooled, 0, 64 * 128 * 4, stream);

    // CSR build: deterministic radix partition + hierarchical scan
    k_cnt  <<<NBLK, WG, 0, stream>>>(edst, E, gcounts);
    k_scanA<<<(NB * NBLK) / 1024, WG, 0, stream>>>(gcounts, bsum);
    k_scanB<<<1, 64, 0, stream>>>(bsum);
    k_scat <<<NBLK, WG, 0, stream>>>(esrc, edst, E, gcounts, bsum, pairs);
    k_build<<<nb, WG, 0, stream>>>(pairs, gcounts, bsum, N, E, offs, srcs, dis);

    // W transposes (bf16)
    k_wt<<<64, WG, 0, stream>>>(W1, wt1);
    k_wt<<<64, WG, 0, stream>>>(W2, wt2);

    // layer 0 via algebraic fold: gather 4-dim y, then transform by W0
    k_y    <<<(N + WG - 1) / WG, WG, 0, stream>>>(an, pos, dis, ybuf, N);
    k_agg0t<<<(N + WG - 1) / WG, WG, 0, stream>>>(ybuf, W0, b0, dis, offs, srcs, bufA, N);
    // layers 1-2
    k_gemm<<<(N + 63) / 64, WG, 0, stream>>>(bufA, wt1, dis, bufB, N);
    k_agg <<<(N + 31) / 32, WG, 0, stream>>>(bufB, b1, dis, offs, srcs, bufA, N);
    k_gemm<<<(N + 63) / 64, WG, 0, stream>>>(bufA, wt2, dis, bufB, N);
    // final agg fused with pooling
    k_aggp<<<(N + 31) / 32, WG, 0, stream>>>(bufB, b2, dis, offs, srcs, batch, pooled, N);

    k_head<<<1, 64, 0, stream>>>(pooled, batch, linW, linb, (float*)d_out, N);
}

// Round 12
// 295.355 us; speedup vs baseline: 1.1886x; 1.1886x over previous
//
#include <hip/hip_runtime.h>
#include <math.h>

#define WG 256
#define NB 256             // radix buckets (node-range 512 each -> N <= 131072)
#define BSHIFT 9
#define NBLK 256           // partition blocks

typedef float vf2 __attribute__((ext_vector_type(2)));
typedef short bf16x8 __attribute__((ext_vector_type(8)));
typedef float f32x4 __attribute__((ext_vector_type(4)));

#define XS_STRIDE 136      // ushort stride, 16B-aligned rows + conflict pad
#define WT_STRIDE 136
#define C_STRIDE 132       // float stride, 16B-aligned

__device__ __forceinline__ int lower_bound_i(const int* __restrict__ a, int n, int key) {
    int lo = 0, hi = n;
    while (lo < hi) { int mid = (lo + hi) >> 1; if (a[mid] < key) lo = mid + 1; else hi = mid; }
    return lo;
}

// ---- fp8 (OCP e4m3) helpers ------------------------------------------------
__device__ __forceinline__ void fp8x8_to_f8(uint2 raw, float* f) {
    vf2 a = __builtin_amdgcn_cvt_pk_f32_fp8((int)raw.x, false);
    vf2 b = __builtin_amdgcn_cvt_pk_f32_fp8((int)raw.x, true);
    vf2 c = __builtin_amdgcn_cvt_pk_f32_fp8((int)raw.y, false);
    vf2 d = __builtin_amdgcn_cvt_pk_f32_fp8((int)raw.y, true);
    f[0]=a.x; f[1]=a.y; f[2]=b.x; f[3]=b.y; f[4]=c.x; f[5]=c.y; f[6]=d.x; f[7]=d.y;
}
__device__ __forceinline__ void fp8x16_to_f(uint4 raw, float* f) {
    uint2 lo, hi;
    lo.x = raw.x; lo.y = raw.y; hi.x = raw.z; hi.y = raw.w;
    fp8x8_to_f8(lo, f);
    fp8x8_to_f8(hi, f + 8);
}
__device__ __forceinline__ unsigned int f4_to_fp8x4(float x, float y, float z, float w) {
    int v = __builtin_amdgcn_cvt_pk_fp8_f32(x, y, 0, false);
    v = __builtin_amdgcn_cvt_pk_fp8_f32(z, w, v, true);
    return (unsigned int)v;
}
__device__ __forceinline__ unsigned short f_to_bf_trunc(float f) {
    return (unsigned short)(__float_as_uint(f) >> 16);
}
__device__ __forceinline__ unsigned short f_to_bf_rne(float f) {
    unsigned int u = __float_as_uint(f);
    u += 0x7FFFu + ((u >> 16) & 1u);
    return (unsigned short)(u >> 16);
}

// ---- CSR build: deterministic radix partition (no global atomics) ----------

__global__ __launch_bounds__(256) void k_cnt(const int* __restrict__ edst, int E,
                                             int* __restrict__ gcounts) {
    __shared__ int hist[NB];
    int t = threadIdx.x, blk = blockIdx.x;
    if (t < NB) hist[t] = 0;
    __syncthreads();
    int chunk = (E + NBLK - 1) / NBLK;
    int e0 = blk * chunk, e1 = min(E, e0 + chunk);
    for (int e = e0 + t; e < e1; e += 256) atomicAdd(&hist[edst[e] >> BSHIFT], 1);
    __syncthreads();
    if (t < NB) gcounts[t * NBLK + blk] = hist[t];
}

__global__ __launch_bounds__(256) void k_scanA(int* __restrict__ gcounts,
                                               int* __restrict__ bsum) {
    __shared__ int wtot[4];
    int t = threadIdx.x;
    int base = blockIdx.x * 1024 + t * 4;
    int4 v = *(const int4*)&gcounts[base];
    int s = v.x + v.y + v.z + v.w;
    int lane = t & 63, wid = t >> 6;
    int x = s;
#pragma unroll
    for (int d = 1; d < 64; d <<= 1) { int y = __shfl_up(x, d); if (lane >= d) x += y; }
    if (lane == 63) wtot[wid] = x;
    __syncthreads();
    int woff = 0;
    for (int w = 0; w < wid; w++) woff += wtot[w];
    int excl = woff + x - s;
    int4 o;
    o.x = excl; o.y = excl + v.x; o.z = o.y + v.y; o.w = o.z + v.z;
    *(int4*)&gcounts[base] = o;
    if (t == 255) bsum[blockIdx.x] = woff + x;
}

__global__ void k_scanB(int* __restrict__ bsum) {
    int t = threadIdx.x;   // 64 threads
    int v = bsum[t];
    int x = v;
#pragma unroll
    for (int d = 1; d < 64; d <<= 1) { int y = __shfl_up(x, d); if (t >= d) x += y; }
    bsum[t] = x - v;
}

// scatter edges packed as (src << 9) | (dst & 511)
__global__ __launch_bounds__(256) void k_scat(const int* __restrict__ esrc,
        const int* __restrict__ edst, int E,
        const int* __restrict__ gcounts, const int* __restrict__ bsum,
        int* __restrict__ pairs) {
    __shared__ int cur[NB];
    int t = threadIdx.x, blk = blockIdx.x;
    if (t < NB) {
        int idx = t * NBLK + blk;
        cur[t] = gcounts[idx] + bsum[idx >> 10];
    }
    __syncthreads();
    int chunk = (E + NBLK - 1) / NBLK;
    int e0 = blk * chunk, e1 = min(E, e0 + chunk);
    for (int e = e0 + t; e < e1; e += 256) {
        int d = edst[e], s = esrc[e];
        int pos = atomicAdd(&cur[d >> BSHIFT], 1);
        pairs[pos] = (s << BSHIFT) | (d & ((1 << BSHIFT) - 1));
    }
}

__global__ __launch_bounds__(256) void k_build(const int* __restrict__ pairs,
        const int* __restrict__ gcounts, const int* __restrict__ bsum, int N, int E,
        int* __restrict__ offs, int* __restrict__ srcs, float* __restrict__ dis) {
    __shared__ int cnt[512];
    __shared__ int wtot[4];
    int b = blockIdx.x, t = threadIdx.x;
    int n0 = b << BSHIFT;
    cnt[2 * t] = 0; cnt[2 * t + 1] = 0;
    __syncthreads();
    int i0 = b * NBLK, i1 = (b + 1) * NBLK;
    int bs = gcounts[i0] + bsum[i0 >> 10];
    int be = gcounts[i1] + bsum[i1 >> 10];
    int m = be - bs;
    const int* pb = &pairs[bs];
    for (int i = t; i < m; i += 256) {
        int p = pb[i];
        atomicAdd(&cnt[p & 511], 1);
    }
    __syncthreads();
    int v0 = cnt[2 * t], v1 = cnt[2 * t + 1];
    int ts = v0 + v1;
    int lane = t & 63, wid = t >> 6;
    int x = ts;
    #pragma unroll
    for (int d = 1; d < 64; d <<= 1) { int y = __shfl_up(x, d); if (lane >= d) x += y; }
    if (lane == 63) wtot[wid] = x;
    __syncthreads();
    int woff = 0;
    for (int w = 0; w < wid; w++) woff += wtot[w];
    int excl = woff + x - ts;
    int o0 = excl, o1 = excl + v0;
    cnt[2 * t] = o0; cnt[2 * t + 1] = o1;
    int n = n0 + 2 * t;
    if (n + 0 < N) { offs[n + 0] = bs + o0; dis[n + 0] = rsqrtf((float)(v0 + 1)); }
    if (n + 1 < N) { offs[n + 1] = bs + o1; dis[n + 1] = rsqrtf((float)(v1 + 1)); }
    if (b == gridDim.x - 1 && t == 255) offs[N] = E;
    __syncthreads();
    for (int i = t; i < m; i += 256) {
        int p = pb[i];
        int pos = atomicAdd(&cnt[p & 511], 1);
        srcs[bs + pos] = p >> BSHIFT;
    }
}

// ---- W transpose to bf16: WT[j][k] = bf16(W[k][j]) -------------------------
__global__ __launch_bounds__(256) void k_wt(const float* __restrict__ W,
                                            unsigned short* __restrict__ wt) {
    int idx = blockIdx.x * 256 + threadIdx.x;
    int k = idx >> 7, j = idx & 127;
    float v = W[k * 128 + j];
    wt[j * 128 + k] = f_to_bf_rne(v);
}

// ---- Layer kernels --------------------------------------------------------

// y[n] = dis[n] * (an, px, py, pz)   — 16B fp32 rows for the 4-dim gather
__global__ void k_y(const float* __restrict__ an, const float* __restrict__ pos,
                    const float* __restrict__ dis, float4* __restrict__ y, int N) {
    int n = blockIdx.x * blockDim.x + threadIdx.x;
    if (n >= N) return;
    float dn = dis[n];
    float4 v;
    v.x = dn * an[n];
    v.y = dn * pos[n * 3 + 0];
    v.z = dn * pos[n * 3 + 1];
    v.w = dn * pos[n * 3 + 2];
    y[n] = v;
}

// Layer0 (algebraic fold): x1[n] = relu(b0 + dis[n]*(y[n]+Σ y[src]) @ W0), fp8.
// 1 thread per node; 4-dim gather (16B rows, L2-resident 1.6MB buffer).
__global__ __launch_bounds__(256) void k_agg0t(const float4* __restrict__ y,
        const float* __restrict__ W0, const float* __restrict__ b0,
        const float* __restrict__ dis, const int* __restrict__ offs,
        const int* __restrict__ srcs, unsigned int* __restrict__ h, int N) {
    int n = blockIdx.x * blockDim.x + threadIdx.x;
    if (n >= N) return;
    float4 acc = y[n];   // self-loop
    int e0 = offs[n], e1 = offs[n + 1];
    int e = e0;
    for (; e + 4 <= e1; e += 4) {
        float4 r0 = y[srcs[e + 0]];
        float4 r1 = y[srcs[e + 1]];
        float4 r2 = y[srcs[e + 2]];
        float4 r3 = y[srcs[e + 3]];
        acc.x += (r0.x + r1.x) + (r2.x + r3.x);
        acc.y += (r0.y + r1.y) + (r2.y + r3.y);
        acc.z += (r0.z + r1.z) + (r2.z + r3.z);
        acc.w += (r0.w + r1.w) + (r2.w + r3.w);
    }
    for (; e < e1; ++e) {
        float4 r = y[srcs[e]];
        acc.x += r.x; acc.y += r.y; acc.z += r.z; acc.w += r.w;
    }
    float dn = dis[n];
    acc.x *= dn; acc.y *= dn; acc.z *= dn; acc.w *= dn;
    // matvec: out[j] = relu(b0[j] + acc · W0[:,j]); W0 loads are wave-uniform
#pragma unroll
    for (int c = 0; c < 8; c++) {
        float o[16];
#pragma unroll
        for (int q = 0; q < 4; q++) {
            const float4 bq = *(const float4*)&b0[c * 16 + q * 4];
            const float4 w0q = *(const float4*)&W0[0 * 128 + c * 16 + q * 4];
            const float4 w1q = *(const float4*)&W0[1 * 128 + c * 16 + q * 4];
            const float4 w2q = *(const float4*)&W0[2 * 128 + c * 16 + q * 4];
            const float4 w3q = *(const float4*)&W0[3 * 128 + c * 16 + q * 4];
            o[q*4+0] = fmaxf(bq.x + acc.x*w0q.x + acc.y*w1q.x + acc.z*w2q.x + acc.w*w3q.x, 0.f);
            o[q*4+1] = fmaxf(bq.y + acc.x*w0q.y + acc.y*w1q.y + acc.z*w2q.y + acc.w*w3q.y, 0.f);
            o[q*4+2] = fmaxf(bq.z + acc.x*w0q.z + acc.y*w1q.z + acc.z*w2q.z + acc.w*w3q.z, 0.f);
            o[q*4+3] = fmaxf(bq.w + acc.x*w0q.w + acc.y*w1q.w + acc.z*w2q.w + acc.w*w3q.w, 0.f);
        }
        uint4 outv;
        outv.x = f4_to_fp8x4(o[0], o[1], o[2], o[3]);
        outv.y = f4_to_fp8x4(o[4], o[5], o[6], o[7]);
        outv.z = f4_to_fp8x4(o[8], o[9], o[10], o[11]);
        outv.w = f4_to_fp8x4(o[12], o[13], o[14], o[15]);
        *(uint4*)&h[(size_t)n * 32 + c * 4] = outv;
    }
}

// MFMA GEMM: h'[n][f] = (relu(x[n]) @ W)[f] * dis[n]
__global__ __launch_bounds__(256) void k_gemm(const unsigned int* __restrict__ x,
                                              const unsigned short* __restrict__ wt,
                                              const float* __restrict__ dis,
                                              unsigned int* __restrict__ h, int N) {
    __shared__ __align__(16) char ldsb[(64 * XS_STRIDE + 128 * WT_STRIDE) * 2];
    unsigned short* xs  = (unsigned short*)ldsb;
    unsigned short* wtl = xs + 64 * XS_STRIDE;
    float* Cs = (float*)ldsb;

    int t = threadIdx.x;
    int n0 = blockIdx.x * 64;

    {
        const uint2* xg = (const uint2*)(x + (size_t)n0 * 32);
        int validq = min(64, N - n0) * 16;
#pragma unroll
        for (int i = 0; i < 4; i++) {
            int idx = t + i * 256;
            int row = idx >> 4, part = idx & 15;
            float f[8];
            if (idx < validq) {
                fp8x8_to_f8(xg[idx], f);
#pragma unroll
                for (int k = 0; k < 8; k++) f[k] = fmaxf(f[k], 0.f);
            } else {
#pragma unroll
                for (int k = 0; k < 8; k++) f[k] = 0.f;
            }
            bf16x8 v;
#pragma unroll
            for (int k = 0; k < 8; k++) v[k] = (short)f_to_bf_trunc(f[k]);
            *(bf16x8*)&xs[row * XS_STRIDE + part * 8] = v;
        }
    }
    {
        const uint4* wg = (const uint4*)wt;
#pragma unroll
        for (int i = 0; i < 8; i++) {
            int idx = t + i * 256;
            int j = idx >> 4, part = idx & 15;
            uint4 v = wg[idx];
            *(uint4*)&wtl[j * WT_STRIDE + part * 8] = v;
        }
    }
    __syncthreads();

    int lane = t & 63, wv = t >> 6;
    int m = lane & 15, quad = lane >> 4;
    int rowbase = wv * 16;

    f32x4 acc[8];
#pragma unroll
    for (int c = 0; c < 8; c++) acc[c] = (f32x4){0.f, 0.f, 0.f, 0.f};

#pragma unroll
    for (int kt = 0; kt < 4; kt++) {
        bf16x8 a = *(bf16x8*)&xs[(rowbase + m) * XS_STRIDE + kt * 32 + quad * 8];
#pragma unroll
        for (int c = 0; c < 8; c++) {
            bf16x8 b = *(bf16x8*)&wtl[(c * 16 + m) * WT_STRIDE + kt * 32 + quad * 8];
            acc[c] = __builtin_amdgcn_mfma_f32_16x16x32_bf16(a, b, acc[c], 0, 0, 0);
        }
    }
    __syncthreads();

#pragma unroll
    for (int c = 0; c < 8; c++) {
#pragma unroll
        for (int r = 0; r < 4; r++) {
            Cs[(rowbase + quad * 4 + r) * C_STRIDE + c * 16 + m] = acc[c][r];
        }
    }
    __syncthreads();

    int fq = t & 31, ng = t >> 5;
#pragma unroll
    for (int i = 0; i < 8; i++) {
        int lrow = ng * 8 + i;
        int n = n0 + lrow;
        if (n < N) {
            float4 v = *(const float4*)&Cs[lrow * C_STRIDE + 4 * fq];
            float dn = dis[n];
            h[(size_t)n * 32 + fq] = f4_to_fp8x4(v.x * dn, v.y * dn, v.z * dn, v.w * dn);
        }
    }
}

// agg[n] = b + dis[n]*(h'[n] + sum_src h'[src]); fp8 out (pre-relu).
// block = 256 = 32 nodes x 8 lanes; lane handles 16 feats (uint4 = 16B loads);
// edge loop unrolled x8 for 8 outstanding gathers per lane.
__global__ __launch_bounds__(256) void k_agg(const unsigned int* __restrict__ h,
                      const float* __restrict__ bias,
                      const float* __restrict__ dis, const int* __restrict__ offs,
                      const int* __restrict__ srcs, unsigned int* __restrict__ agg, int N) {
    int fq = threadIdx.x & 7, ng = threadIdx.x >> 3;
    int n = blockIdx.x * 32 + ng;
    if (n >= N) return;
    const uint4* hp4 = (const uint4*)h;
    float acc[16], tmp[16];
    fp8x16_to_f(hp4[(size_t)n * 8 + fq], acc);
    int e0 = offs[n], e1 = offs[n + 1];
    int e = e0;
    for (; e + 8 <= e1; e += 8) {
        uint4 r0 = hp4[(size_t)srcs[e + 0] * 8 + fq];
        uint4 r1 = hp4[(size_t)srcs[e + 1] * 8 + fq];
        uint4 r2 = hp4[(size_t)srcs[e + 2] * 8 + fq];
        uint4 r3 = hp4[(size_t)srcs[e + 3] * 8 + fq];
        uint4 r4 = hp4[(size_t)srcs[e + 4] * 8 + fq];
        uint4 r5 = hp4[(size_t)srcs[e + 5] * 8 + fq];
        uint4 r6 = hp4[(size_t)srcs[e + 6] * 8 + fq];
        uint4 r7 = hp4[(size_t)srcs[e + 7] * 8 + fq];
        fp8x16_to_f(r0, tmp);
#pragma unroll
        for (int k = 0; k < 16; k++) acc[k] += tmp[k];
        fp8x16_to_f(r1, tmp);
#pragma unroll
        for (int k = 0; k < 16; k++) acc[k] += tmp[k];
        fp8x16_to_f(r2, tmp);
#pragma unroll
        for (int k = 0; k < 16; k++) acc[k] += tmp[k];
        fp8x16_to_f(r3, tmp);
#pragma unroll
        for (int k = 0; k < 16; k++) acc[k] += tmp[k];
        fp8x16_to_f(r4, tmp);
#pragma unroll
        for (int k = 0; k < 16; k++) acc[k] += tmp[k];
        fp8x16_to_f(r5, tmp);
#pragma unroll
        for (int k = 0; k < 16; k++) acc[k] += tmp[k];
        fp8x16_to_f(r6, tmp);
#pragma unroll
        for (int k = 0; k < 16; k++) acc[k] += tmp[k];
        fp8x16_to_f(r7, tmp);
#pragma unroll
        for (int k = 0; k < 16; k++) acc[k] += tmp[k];
    }
    for (; e + 4 <= e1; e += 4) {
        uint4 r0 = hp4[(size_t)srcs[e + 0] * 8 + fq];
        uint4 r1 = hp4[(size_t)srcs[e + 1] * 8 + fq];
        uint4 r2 = hp4[(size_t)srcs[e + 2] * 8 + fq];
        uint4 r3 = hp4[(size_t)srcs[e + 3] * 8 + fq];
        fp8x16_to_f(r0, tmp);
#pragma unroll
        for (int k = 0; k < 16; k++) acc[k] += tmp[k];
        fp8x16_to_f(r1, tmp);
#pragma unroll
        for (int k = 0; k < 16; k++) acc[k] += tmp[k];
        fp8x16_to_f(r2, tmp);
#pragma unroll
        for (int k = 0; k < 16; k++) acc[k] += tmp[k];
        fp8x16_to_f(r3, tmp);
#pragma unroll
        for (int k = 0; k < 16; k++) acc[k] += tmp[k];
    }
    for (; e < e1; ++e) {
        fp8x16_to_f(hp4[(size_t)srcs[e] * 8 + fq], tmp);
#pragma unroll
        for (int k = 0; k < 16; k++) acc[k] += tmp[k];
    }
    float dn = dis[n];
    float bv[16];
    *(float4*)&bv[0]  = *(const float4*)&bias[fq * 16 + 0];
    *(float4*)&bv[4]  = *(const float4*)&bias[fq * 16 + 4];
    *(float4*)&bv[8]  = *(const float4*)&bias[fq * 16 + 8];
    *(float4*)&bv[12] = *(const float4*)&bias[fq * 16 + 12];
    float o[16];
#pragma unroll
    for (int k = 0; k < 16; k++) o[k] = bv[k] + dn * acc[k];
    uint4 outv;
    outv.x = f4_to_fp8x4(o[0], o[1], o[2], o[3]);
    outv.y = f4_to_fp8x4(o[4], o[5], o[6], o[7]);
    outv.z = f4_to_fp8x4(o[8], o[9], o[10], o[11]);
    outv.w = f4_to_fp8x4(o[12], o[13], o[14], o[15]);
    *(uint4*)&agg[(size_t)n * 32 + fq * 4] = outv;
}

// ---- Pool + head ----------------------------------------------------------

// grid = 64 graphs x 8 chunks; block 256 = 8 row-groups x 32 lanes (uint loads)
__global__ void k_pool(const unsigned int* __restrict__ x, const int* __restrict__ batch,
                       float* __restrict__ pooled, int N) {
    int g = blockIdx.x >> 3, c = blockIdx.x & 7;
    int start = lower_bound_i(batch, N, g);
    int end   = lower_bound_i(batch, N, g + 1);
    int len = end - start;
    int cb = start + (int)((long)len * c / 8);
    int ce = start + (int)((long)len * (c + 1) / 8);
    int fq = threadIdx.x & 31, rg = threadIdx.x >> 5;
    float acc[4] = {0.f, 0.f, 0.f, 0.f};
    for (int n = cb + rg; n < ce; n += 8) {
        unsigned int u = x[(size_t)n * 32 + fq];
        vf2 lo = __builtin_amdgcn_cvt_pk_f32_fp8((int)u, false);
        vf2 hi = __builtin_amdgcn_cvt_pk_f32_fp8((int)u, true);
        acc[0] += fmaxf(lo.x, 0.f); acc[1] += fmaxf(lo.y, 0.f);
        acc[2] += fmaxf(hi.x, 0.f); acc[3] += fmaxf(hi.y, 0.f);
    }
    __shared__ float sh[8 * 128];
#pragma unroll
    for (int k = 0; k < 4; k++) sh[rg * 128 + fq * 4 + k] = acc[k];
    __syncthreads();
    int t = threadIdx.x;
    if (t < 128) {
        float s = 0.f;
#pragma unroll
        for (int r = 0; r < 8; r++) s += sh[r * 128 + t];
        atomicAdd(&pooled[g * 128 + t], s);
    }
}

__global__ void k_head(const float* __restrict__ pooled, const int* __restrict__ batch,
                       const float* __restrict__ linW, const float* __restrict__ linb,
                       float* __restrict__ out, int N) {
    int g = threadIdx.x;
    if (g >= 64) return;
    int start = lower_bound_i(batch, N, g);
    int end   = lower_bound_i(batch, N, g + 1);
    float cnt = fmaxf((float)(end - start), 1.0f);
    float logits[8];
#pragma unroll
    for (int j = 0; j < 8; j++) logits[j] = linb[j];
    for (int f = 0; f < 128; f++) {
        float p = pooled[g * 128 + f] / cnt;
#pragma unroll
        for (int j = 0; j < 8; j++) logits[j] += p * linW[f * 8 + j];
    }
    float m = logits[0];
#pragma unroll
    for (int j = 1; j < 8; j++) m = fmaxf(m, logits[j]);
    float s = 0.f;
    float e[8];
#pragma unroll
    for (int j = 0; j < 8; j++) { e[j] = expf(logits[j] - m); s += e[j]; }
#pragma unroll
    for (int j = 0; j < 8; j++) out[g * 8 + j] = e[j] / s;
}

// ---- Launch ---------------------------------------------------------------

extern "C" void kernel_launch(void* const* d_in, const int* in_sizes, int n_in,
                              void* d_out, int out_size, void* d_ws, size_t ws_size,
                              hipStream_t stream) {
    const float* an   = (const float*)d_in[0];
    const float* pos  = (const float*)d_in[1];
    const float* W0   = (const float*)d_in[2];
    const float* b0   = (const float*)d_in[3];
    const float* W1   = (const float*)d_in[4];
    const float* b1   = (const float*)d_in[5];
    const float* W2   = (const float*)d_in[6];
    const float* b2   = (const float*)d_in[7];
    const float* linW = (const float*)d_in[8];
    const float* linb = (const float*)d_in[9];
    const int*   ei   = (const int*)d_in[10];
    const int*   batch= (const int*)d_in[11];

    int N = in_sizes[0];
    int E = in_sizes[10] / 2;
    const int* esrc = ei;
    const int* edst = ei + E;
    int nb = (N + (1 << BSHIFT) - 1) >> BSHIFT;   // 196 for N=100000

    char* p = (char*)d_ws;
    auto carve = [&](size_t bytes) -> void* {
        void* r = (void*)p;
        p += (bytes + 255) & ~(size_t)255;
        return r;
    };
    unsigned int* bufA = (unsigned int*)carve((size_t)N * 128);   // fp8 rows
    unsigned int* bufB = (unsigned int*)carve((size_t)N * 128);
    float* dis    = (float*)carve((size_t)N * 4);
    float4* ybuf  = (float4*)carve((size_t)N * 16);
    int*   offs   = (int*)  carve((size_t)(N + 1) * 4);
    int*   srcs   = (int*)  carve((size_t)E * 4);
    int*   pairs  = (int*)  carve((size_t)E * 4);
    int*   gcounts= (int*)  carve((size_t)NB * NBLK * 4);
    int*   bsum   = (int*)  carve(64 * 4);
    unsigned short* wt1 = (unsigned short*)carve(128 * 128 * 2);
    unsigned short* wt2 = (unsigned short*)carve(128 * 128 * 2);
    float* pooled = (float*)carve(64 * 128 * 4);

    hipMemsetAsync(pooled, 0, 64 * 128 * 4, stream);

    // CSR build: deterministic radix partition + hierarchical scan
    k_cnt  <<<NBLK, WG, 0, stream>>>(edst, E, gcounts);
    k_scanA<<<(NB * NBLK) / 1024, WG, 0, stream>>>(gcounts, bsum);
    k_scanB<<<1, 64, 0, stream>>>(bsum);
    k_scat <<<NBLK, WG, 0, stream>>>(esrc, edst, E, gcounts, bsum, pairs);
    k_build<<<nb, WG, 0, stream>>>(pairs, gcounts, bsum, N, E, offs, srcs, dis);

    // W transposes (bf16)
    k_wt<<<64, WG, 0, stream>>>(W1, wt1);
    k_wt<<<64, WG, 0, stream>>>(W2, wt2);

    // layer 0 via algebraic fold: gather 4-dim y, then transform by W0
    k_y    <<<(N + WG - 1) / WG, WG, 0, stream>>>(an, pos, dis, ybuf, N);
    k_agg0t<<<(N + WG - 1) / WG, WG, 0, stream>>>(ybuf, W0, b0, dis, offs, srcs, bufA, N);
    // layers 1-2 (separate agg/gemm; pool NOT fused — R11 showed LDS-atomic serialization)
    k_gemm<<<(N + 63) / 64, WG, 0, stream>>>(bufA, wt1, dis, bufB, N);
    k_agg <<<(N + 31) / 32, WG, 0, stream>>>(bufB, b1, dis, offs, srcs, bufA, N);
    k_gemm<<<(N + 63) / 64, WG, 0, stream>>>(bufA, wt2, dis, bufB, N);
    k_agg <<<(N + 31) / 32, WG, 0, stream>>>(bufB, b2, dis, offs, srcs, bufA, N);

    // pool + head
    k_pool<<<64 * 8, WG, 0, stream>>>(bufA, batch, pooled, N);
    k_head<<<1, 64, 0, stream>>>(pooled, batch, linW, linb, (float*)d_out, N);
}